// Round 19
// baseline (119.680 us; speedup 1.0000x reference)
//
#include <hip/hip_runtime.h>
#include <math.h>

#define DIN   128
#define DOUT  64
#define NHEAD 4
#define HD    16
#define BKT_SH 7
#define BKT_SZ 128

typedef __attribute__((ext_vector_type(8))) short bf16x8;
typedef __attribute__((ext_vector_type(8))) unsigned short u16x8;
typedef __attribute__((ext_vector_type(4))) float f32x4;

__device__ __forceinline__ unsigned short f2bf(float f) {
    union { float f; unsigned u; } v; v.f = f;
    unsigned r = v.u + 0x7FFF + ((v.u >> 16) & 1);   // round-to-nearest-even
    return (unsigned short)(r >> 16);
}
__device__ __forceinline__ float bf2f(unsigned short s) {
    union { unsigned u; float f; } v; v.u = ((unsigned)s) << 16; return v.f;
}

// ---------------- init: wT bf16 (blocks 0..95) + zero bucket_cnt ------------
__global__ __launch_bounds__(256)
void k_init(const float* __restrict__ Ws, const float* __restrict__ Wd,
            const float* __restrict__ Wl, short* __restrict__ wT,
            int* __restrict__ bucket_cnt, int NBK) {
    const int bid = blockIdx.x, tid = threadIdx.x;
    if (bid < 96) {
        const int idx = bid * 256 + tid;              // 96*256 = 24576 = 192*128
        const int n = idx >> 7, k = idx & 127;
        float v;
        if (n < 64)       v = Ws[k * DOUT + n];
        else if (n < 128) v = Wd[k * DOUT + (n - 64)];
        else              v = Wl[k * DOUT + (n - 128)];
        wT[idx] = (short)f2bf(v);
        return;
    }
    const int i = (bid - 96) * 256 + tid;
    if (i <= NBK) bucket_cnt[i] = 0;
}

// ---------------- fused: node_proj (even blocks) + bucket count (odd) -------
// proj role: 4 waves x 16 nodes = 64 nodes/block. wT staged in LDS ONCE per
// block in MFMA-fragment order. count role: LDS hist over buckets.
__global__ __launch_bounds__(256)
void k_proj_cnt(const float* __restrict__ x, const short* __restrict__ wT,
                const float* __restrict__ bs, const float* __restrict__ bd,
                const float* __restrict__ bl, const float* __restrict__ Wa,
                unsigned short* __restrict__ packed_bf,
                float* __restrict__ xd, float* __restrict__ alpha_s,
                float* __restrict__ alpha_d, float* __restrict__ h_out, int N,
                const int* __restrict__ dst, int* __restrict__ bucket_cnt,
                int E, int NPJ, int NCB, int NBK) {
    __shared__ short xs[64 * 136];                    // 17.4 KB (proj x tile)
    __shared__ short wtl[48 * 512];                   // 48 KB (proj W frags)
    __shared__ int  lhist[392];                       // (count)
    const int bid = blockIdx.x, tid = threadIdx.x;

    if (bid & 1) {
        // ---------------- count role ----------------
        const int ci = bid >> 1;
        if (ci >= NCB) return;
        for (int i = tid; i < NBK; i += 256) lhist[i] = 0;
        __syncthreads();
        const int base0 = ci * 4096;
#pragma unroll
        for (int k = 0; k < 4; ++k) {
            const int e0 = base0 + k * 1024 + tid * 4;
            if (e0 + 3 < E) {
                const int4 d = *(const int4*)&dst[e0];
                atomicAdd(&lhist[d.x >> BKT_SH], 1);
                atomicAdd(&lhist[d.y >> BKT_SH], 1);
                atomicAdd(&lhist[d.z >> BKT_SH], 1);
                atomicAdd(&lhist[d.w >> BKT_SH], 1);
            } else {
                for (int e = e0; e < E; ++e) atomicAdd(&lhist[dst[e] >> BKT_SH], 1);
            }
        }
        __syncthreads();
        for (int i = tid; i < NBK; i += 256)
            if (lhist[i]) atomicAdd(&bucket_cnt[i], lhist[i]);
        return;
    }

    // ---------------- proj role ----------------
    const int pj = bid >> 1;
    if (pj >= NPJ) return;
    const int wave = tid >> 6, lane = tid & 63;
    const int lam = lane & 15, g = lane >> 4;
    const int n0 = pj * 64;

    {
        const int r = tid >> 2, c0 = (tid & 3) * 32;
        const int nn = n0 + r;
#pragma unroll
        for (int j = 0; j < 8; ++j) {
            float4 v = make_float4(0.f, 0.f, 0.f, 0.f);
            if (nn < N) v = ((const float4*)x)[(size_t)nn * 32 + (c0 >> 2) + j];
            short4 h4;
            h4.x = (short)f2bf(v.x); h4.y = (short)f2bf(v.y);
            h4.z = (short)f2bf(v.z); h4.w = (short)f2bf(v.w);
            *(short4*)&xs[r * 136 + c0 + j * 4] = h4;
        }
    }
#pragma unroll
    for (int k = 0; k < 12; ++k) {
        const int s = k * 256 + tid;                  // 0..3071
        const int f = s >> 6, l = s & 63;
        const int c = f >> 2, ks = f & 3;
        const int go = (c * 16 + (l & 15)) * 128 + ks * 32 + (l >> 4) * 8;
        *(u16x8*)&wtl[s * 8] = *(const u16x8*)&wT[go];
    }
    __syncthreads();

    bf16x8 afr[4];
#pragma unroll
    for (int ks = 0; ks < 4; ++ks)
        afr[ks] = *(const bf16x8*)&xs[(wave * 16 + lam) * 136 + ks * 32 + g * 8];

    f32x4 acc[12];
#pragma unroll
    for (int c = 0; c < 12; ++c) acc[c] = (f32x4){0.f, 0.f, 0.f, 0.f};

#pragma unroll
    for (int c = 0; c < 12; ++c) {
#pragma unroll
        for (int ks = 0; ks < 4; ++ks) {
            const bf16x8 b = *(const bf16x8*)&wtl[(((c * 4 + ks) << 6) + lane) * 8];
            acc[c] = __builtin_amdgcn_mfma_f32_16x16x32_bf16(afr[ks], b, acc[c], 0, 0, 0);
        }
    }

    float bsv[4], bdv[4], blv[4];
#pragma unroll
    for (int c = 0; c < 4; ++c) {
        bsv[c] = bs[c * 16 + lam];
        bdv[c] = bd[c * 16 + lam];
        blv[c] = bl[c * 16 + lam];
    }
    const float waS = Wa[lam], waD = Wa[16 + lam];
    const int cc_base = (lam >> 2), t_sl = lam & 3;

#pragma unroll
    for (int i = 0; i < 4; ++i) {
        const int node = n0 + wave * 16 + g * 4 + i;
        float xsv[4], xdv[4], hv[4];
#pragma unroll
        for (int c = 0; c < 4; ++c) {
            xsv[c] = acc[c][i]     + bsv[c];
            xdv[c] = acc[4 + c][i] + bdv[c];
            hv[c]  = acc[8 + c][i] + blv[c];
        }
        float p0 = hv[0] * waS, p1 = hv[1] * waS, p2 = hv[2] * waS, p3 = hv[3] * waS;
        float q0 = hv[0] * waD, q1 = hv[1] * waD, q2 = hv[2] * waD, q3 = hv[3] * waD;
#pragma unroll
        for (int off = 1; off < 16; off <<= 1) {
            p0 += __shfl_xor(p0, off); p1 += __shfl_xor(p1, off);
            p2 += __shfl_xor(p2, off); p3 += __shfl_xor(p3, off);
            q0 += __shfl_xor(q0, off); q1 += __shfl_xor(q1, off);
            q2 += __shfl_xor(q2, off); q3 += __shfl_xor(q3, off);
        }
        if (node < N) {
            const size_t rowb = (size_t)node * 128;
#pragma unroll
            for (int c = 0; c < 4; ++c) {
                const int cc = c * 4 + cc_base;
                packed_bf[rowb + cc * 8 + t_sl]     = f2bf(xsv[c]);
                packed_bf[rowb + cc * 8 + 4 + t_sl] = f2bf(hv[c]);
                xd   [(size_t)node * DOUT + c * 16 + lam] = xdv[c];
                h_out[(size_t)node * DOUT + c * 16 + lam] = hv[c];
            }
            if (lam == 0) {
                *(f32x4*)&alpha_s[(size_t)node * NHEAD] = (f32x4){p0, p1, p2, p3};
                *(f32x4*)&alpha_d[(size_t)node * NHEAD] = (f32x4){q0, q1, q2, q3};
            }
        }
    }
}

// ---------------- scan over buckets (single block, <=512 buckets) -----------
__global__ __launch_bounds__(512)
void k_scan_buckets(const int* __restrict__ bucket_cnt,
                    int* __restrict__ bucket_base, int* __restrict__ bucket_cursor,
                    int NBK) {
    __shared__ int wsum[8];
    const int tid = threadIdx.x, lane = tid & 63, wid = tid >> 6;
    int v = (tid < NBK) ? bucket_cnt[tid] : 0;
    int incl = v;
#pragma unroll
    for (int off = 1; off < 64; off <<= 1) {
        int t = __shfl_up(incl, off);
        if (lane >= off) incl += t;
    }
    if (lane == 63) wsum[wid] = incl;
    __syncthreads();
    if (tid < 8) {
        int t = wsum[tid];
#pragma unroll
        for (int off = 1; off < 8; off <<= 1) {
            int u = __shfl_up(t, off);
            if (tid >= off) t += u;
        }
        wsum[tid] = t;
    }
    __syncthreads();
    const int base = (wid > 0) ? wsum[wid - 1] : 0;
    const int excl = incl - v + base;
    if (tid < NBK) {
        bucket_base[tid]   = excl;
        bucket_cursor[tid] = excl;
    }
    if (tid == 0) bucket_base[NBK] = wsum[7];
}

// ---------------- bucket scatter: (src,dst) pairs into bucket regions -------
__global__ __launch_bounds__(256)
void k_bucket_scatter(const int* __restrict__ src, const int* __restrict__ dst,
                      int* __restrict__ bucket_cursor, int2* __restrict__ pairs,
                      int E, int NBK) {
    __shared__ int lhist[392];
    __shared__ int lcur[392];
    const int tid = threadIdx.x;
    const int base0 = blockIdx.x * 4096;
    for (int i = tid; i < NBK; i += 256) lhist[i] = 0;
    __syncthreads();
#pragma unroll
    for (int k = 0; k < 4; ++k) {
        const int e0 = base0 + k * 1024 + tid * 4;
        if (e0 + 3 < E) {
            const int4 d = *(const int4*)&dst[e0];
            atomicAdd(&lhist[d.x >> BKT_SH], 1);
            atomicAdd(&lhist[d.y >> BKT_SH], 1);
            atomicAdd(&lhist[d.z >> BKT_SH], 1);
            atomicAdd(&lhist[d.w >> BKT_SH], 1);
        } else {
            for (int e = e0; e < E; ++e) atomicAdd(&lhist[dst[e] >> BKT_SH], 1);
        }
    }
    __syncthreads();
    for (int i = tid; i < NBK; i += 256)
        lcur[i] = lhist[i] ? atomicAdd(&bucket_cursor[i], lhist[i]) : 0;
    __syncthreads();
#pragma unroll
    for (int k = 0; k < 4; ++k) {
        const int e0 = base0 + k * 1024 + tid * 4;
        if (e0 + 3 < E) {
            const int4 s = *(const int4*)&src[e0];
            const int4 d = *(const int4*)&dst[e0];
            int p;
            p = atomicAdd(&lcur[d.x >> BKT_SH], 1); pairs[p] = make_int2(s.x, d.x);
            p = atomicAdd(&lcur[d.y >> BKT_SH], 1); pairs[p] = make_int2(s.y, d.y);
            p = atomicAdd(&lcur[d.z >> BKT_SH], 1); pairs[p] = make_int2(s.z, d.z);
            p = atomicAdd(&lcur[d.w >> BKT_SH], 1); pairs[p] = make_int2(s.w, d.w);
        } else {
            for (int e = e0; e < E; ++e) {
                const int d = dst[e];
                const int p = atomicAdd(&lcur[d >> BKT_SH], 1);
                pairs[p] = make_int2(src[e], d);
            }
        }
    }
}

// ---------------- per-bucket: degi hist -> row_ptr + ranked srcs write ------
__global__ __launch_bounds__(256)
void k_bucket_rank(const int2* __restrict__ pairs, const int* __restrict__ bucket_base,
                   int* __restrict__ row_ptr, int* __restrict__ srcs,
                   int N, int NBK) {
    __shared__ int hist[BKT_SZ];
    __shared__ int cursor[BKT_SZ];
    __shared__ int wtot[2];
    const int b = blockIdx.x, tid = threadIdx.x;
    const int n0 = b << BKT_SH;
    const int ebase = bucket_base[b];
    const int ecnt  = bucket_base[b + 1] - ebase;

    if (tid < BKT_SZ) hist[tid] = 0;
    __syncthreads();
    for (int i = tid; i < ecnt; i += 256)
        atomicAdd(&hist[pairs[ebase + i].y & (BKT_SZ - 1)], 1);
    __syncthreads();

    int v = 0, incl = 0;
    const int lane = tid & 63, wid = tid >> 6;
    if (tid < BKT_SZ) {
        v = hist[tid];
        incl = v;
#pragma unroll
        for (int off = 1; off < 64; off <<= 1) {
            int t = __shfl_up(incl, off);
            if (lane >= off) incl += t;
        }
        if (lane == 63) wtot[wid] = incl;
    }
    __syncthreads();
    if (tid < BKT_SZ) {
        const int excl = incl - v + ((wid == 1) ? wtot[0] : 0);
        if (n0 + tid < N) row_ptr[n0 + tid] = ebase + excl;
        cursor[tid] = excl;
    }
    if (b == NBK - 1 && tid == 0) row_ptr[N] = bucket_base[NBK];
    __syncthreads();

    for (int i = tid; i < ecnt; i += 256) {
        const int2 pr = pairs[ebase + i];
        const int slot = atomicAdd(&cursor[pr.y & (BKT_SZ - 1)], 1);
        srcs[ebase + slot] = pr.x;
    }
}

// ---------------- fused per-dst aggregation: 4 nodes/wave, 4 edges/iter -----
// lane = (g=edge group, hd=lam>>2, q=lam&3); lane owns dims hd*16+q*4..+3.
// alpha_s recomputed in-register from packed h (no gather); combined score
// reduction: p = sum(er*Wa[32..] + h*Wa[0..]) == p_er + alpha_s[src].
// prefetch distance 3 (rotating pipeline: no spill).
__global__ __launch_bounds__(256, 8)
void k_aggregate(const int* __restrict__ row_ptr, const int* __restrict__ srcs,
                 const unsigned short* __restrict__ packed_bf, // [N][128]
                 const float* __restrict__ xd,                 // [N][64]
                 const float* __restrict__ alpha_d,
                 const float* __restrict__ Wa, const float* __restrict__ ba,
                 float* __restrict__ edge_s, float* __restrict__ out, int N) {
    const int lane = threadIdx.x & 63;
    const int wave = threadIdx.x >> 6;
    const int g = lane >> 4, lam = lane & 15;
    const int hd = lam >> 2, q = lam & 3;

    const float4 waS4 = *(const float4*)&Wa[q * 4];        // sf segment
    const float4 waE4 = *(const float4*)&Wa[32 + q * 4];   // ef segment
    const float ba0 = ba[0];

    for (int k = 0; k < 4; ++k) {
        const int n = blockIdx.x * 16 + wave * 4 + k;
        if (n >= N) continue;

        const int start = row_ptr[n];
        const int end   = row_ptr[n + 1];
        const int deg = end - start;
        const int last = end - 1;

        const float4 xd4 = *(const float4*)&xd[(size_t)n * DOUT + lam * 4];
        const float adb  = alpha_d[n * NHEAD + hd] + ba0;

        float es0=0.f,es1=0.f,es2=0.f,es3=0.f;
        float o0=0.f,o1=0.f,o2=0.f,o3=0.f;
        float s = 0.f;

        const int niter = (deg + 3) >> 2;
        int e = start + g;

        float vm0=0.f, vm1=0.f, vm2=0.f;
        u16x8 pk0=(u16x8){0,0,0,0,0,0,0,0}, pk1=pk0, pk2=pk0;
        if (niter > 0) {
            {
                vm0 = (e < end) ? 1.f : 0.f;
                const int sn = srcs[min(e, last)];
                pk0 = *(const u16x8*)&packed_bf[(size_t)sn * 128 + lam * 8];
            }
            {
                const int e1 = e + 4;
                vm1 = (e1 < end) ? 1.f : 0.f;
                const int sn = srcs[min(e1, last)];
                pk1 = *(const u16x8*)&packed_bf[(size_t)sn * 128 + lam * 8];
            }
            {
                const int e2 = e + 8;
                vm2 = (e2 < end) ? 1.f : 0.f;
                const int sn = srcs[min(e2, last)];
                pk2 = *(const u16x8*)&packed_bf[(size_t)sn * 128 + lam * 8];
            }
        }

        for (int it = 0; it < niter; ++it) {
            float vmn = 0.f;
            u16x8 pkn = (u16x8){0,0,0,0,0,0,0,0};
            const int e3 = e + 12;
            if (it + 3 < niter) {
                vmn = (e3 < end) ? 1.f : 0.f;
                const int sn = srcs[min(e3, last)];
                pkn = *(const u16x8*)&packed_bf[(size_t)sn * 128 + lam * 8];
            }

            const float t0 = __expf(2.f * (bf2f(pk0[0]) + xd4.x));
            const float t1 = __expf(2.f * (bf2f(pk0[1]) + xd4.y));
            const float t2 = __expf(2.f * (bf2f(pk0[2]) + xd4.z));
            const float t3 = __expf(2.f * (bf2f(pk0[3]) + xd4.w));
            const float er0 = fmaf(-2.f, __builtin_amdgcn_rcpf(t0 + 1.f), 1.f);
            const float er1 = fmaf(-2.f, __builtin_amdgcn_rcpf(t1 + 1.f), 1.f);
            const float er2 = fmaf(-2.f, __builtin_amdgcn_rcpf(t2 + 1.f), 1.f);
            const float er3 = fmaf(-2.f, __builtin_amdgcn_rcpf(t3 + 1.f), 1.f);
            es0 = fmaf(er0, vm0, es0); es1 = fmaf(er1, vm0, es1);
            es2 = fmaf(er2, vm0, es2); es3 = fmaf(er3, vm0, es3);

            const float h0 = bf2f(pk0[4]), h1 = bf2f(pk0[5]);
            const float h2 = bf2f(pk0[6]), h3 = bf2f(pk0[7]);

            // combined score partial: er-part (Wa[32..]) + sf-part (Wa[0..])
            float p = er0 * waE4.x;
            p = fmaf(er1, waE4.y, p);
            p = fmaf(er2, waE4.z, p);
            p = fmaf(er3, waE4.w, p);
            p = fmaf(h0, waS4.x, p);
            p = fmaf(h1, waS4.y, p);
            p = fmaf(h2, waS4.z, p);
            p = fmaf(h3, waS4.w, p);
            p += __shfl_xor(p, 1);
            p += __shfl_xor(p, 2);

            float a = adb + p;
            a = (a >= 0.f) ? a : 0.01f * a;            // leaky relu
            const float w = __expf(a) * vm0;
            s += w;
            o0 = fmaf(w, h0, o0); o1 = fmaf(w, h1, o1);
            o2 = fmaf(w, h2, o2); o3 = fmaf(w, h3, o3);

            vm0 = vm1; pk0 = pk1;
            vm1 = vm2; pk1 = pk2;
            vm2 = vmn; pk2 = pkn;
            e += 4;
        }

#pragma unroll
        for (int off = 16; off < 64; off <<= 1) {
            es0 += __shfl_xor(es0, off); es1 += __shfl_xor(es1, off);
            es2 += __shfl_xor(es2, off); es3 += __shfl_xor(es3, off);
            o0  += __shfl_xor(o0,  off); o1  += __shfl_xor(o1,  off);
            o2  += __shfl_xor(o2,  off); o3  += __shfl_xor(o3,  off);
            s   += __shfl_xor(s,   off);
        }

        if (g == 0) {
            const float inv_s = __builtin_amdgcn_rcpf(fmaxf(s, 1e-38f));
            const float inv_d = __builtin_amdgcn_rcpf(fmaxf((float)deg, 1.0f));
            const size_t od = (size_t)n * DOUT + lam * 4;
            *(f32x4*)&out[od]    = (f32x4){o0 * inv_s, o1 * inv_s, o2 * inv_s, o3 * inv_s};
            *(f32x4*)&edge_s[od] = (f32x4){es0 * inv_d, es1 * inv_d, es2 * inv_d, es3 * inv_d};
        }
    }
}

extern "C" void kernel_launch(void* const* d_in, const int* in_sizes, int n_in,
                              void* d_out, int out_size, void* d_ws, size_t ws_size,
                              hipStream_t stream) {
    const float* x  = (const float*)d_in[0];
    const int*   src= (const int*)  d_in[1];
    const int*   dst= (const int*)  d_in[2];
    const float* Ws = (const float*)d_in[3];
    const float* bs = (const float*)d_in[4];
    const float* Wd = (const float*)d_in[5];
    const float* bd = (const float*)d_in[6];
    const float* Wl = (const float*)d_in[7];
    const float* bl = (const float*)d_in[8];
    const float* Wa = (const float*)d_in[9];
    const float* ba = (const float*)d_in[10];

    const int N = in_sizes[0] / DIN;
    const int E = in_sizes[1];
    const int NBK = (N + BKT_SZ - 1) >> BKT_SH;       // buckets (<=512)

    float* out_f = (float*)d_out;
    float* edge_s_out = out_f;                        // chunk 0: [N,64]
    float* out_attn   = out_f + (size_t)N * DOUT;     // chunk 1: [N,64]
    float* h_out      = out_f + 2 * (size_t)N * DOUT; // chunk 2: [N,64]

    char* ws = (char*)d_ws;
    size_t o = 0;
    unsigned short* packed_bf = (unsigned short*)(ws + o); o += (size_t)N * 128 * 2;
    float* xd      = (float*)(ws + o); o += (size_t)N * DOUT * 4;
    float* alpha_s = (float*)(ws + o); o += (size_t)N * NHEAD * 4;
    float* alpha_d = (float*)(ws + o); o += (size_t)N * NHEAD * 4;
    int*   row_ptr = (int*)  (ws + o); o += (size_t)(N + 1) * 4;
    int*   srcs    = (int*)  (ws + o); o += (size_t)E * 4;
    int2*  pairs   = (int2*) (ws + o); o += (size_t)E * 8;
    int*   bucket_cnt    = (int*)(ws + o); o += 512 * 4;
    int*   bucket_base   = (int*)(ws + o); o += 513 * 4;
    int*   bucket_cursor = (int*)(ws + o); o += 512 * 4;
    short* wT      = (short*)(ws + o); o += (size_t)192 * 128 * 2;

    k_init<<<96 + (NBK + 256) / 256, 256, 0, stream>>>(Ws, Wd, Wl, wT, bucket_cnt, NBK);

    const int NPJ = (N + 63) / 64;             // proj blocks (64 nodes each)
    const int NCB = (E + 4095) / 4096;         // count blocks (4096 edges each)
    const int GC  = 2 * ((NPJ > NCB) ? NPJ : NCB);
    k_proj_cnt<<<GC, 256, 0, stream>>>(x, wT, bs, bd, bl, Wa,
                                       packed_bf, xd, alpha_s, alpha_d, h_out, N,
                                       dst, bucket_cnt, E, NPJ, NCB, NBK);

    k_scan_buckets<<<1, 512, 0, stream>>>(bucket_cnt, bucket_base, bucket_cursor, NBK);

    k_bucket_scatter<<<NCB, 256, 0, stream>>>(src, dst, bucket_cursor, pairs, E, NBK);

    k_bucket_rank<<<NBK, 256, 0, stream>>>(pairs, bucket_base, row_ptr, srcs, N, NBK);

    k_aggregate<<<(N + 15) / 16, 256, 0, stream>>>(row_ptr, srcs, packed_bf, xd,
                                                   alpha_d, Wa, ba,
                                                   edge_s_out, out_attn, N);
}

// Round 20
// 110.722 us; speedup vs baseline: 1.0809x; 1.0809x over previous
//
#include <hip/hip_runtime.h>
#include <math.h>

#define DIN   128
#define DOUT  64
#define NHEAD 4
#define HD    16
#define BKT_SH 7
#define BKT_SZ 128

typedef __attribute__((ext_vector_type(8))) short bf16x8;
typedef __attribute__((ext_vector_type(8))) unsigned short u16x8;
typedef __attribute__((ext_vector_type(4))) float f32x4;

__device__ __forceinline__ unsigned short f2bf(float f) {
    union { float f; unsigned u; } v; v.f = f;
    unsigned r = v.u + 0x7FFF + ((v.u >> 16) & 1);   // round-to-nearest-even
    return (unsigned short)(r >> 16);
}
__device__ __forceinline__ float bf2f(unsigned short s) {
    union { unsigned u; float f; } v; v.u = ((unsigned)s) << 16; return v.f;
}

// ---------------- init: wT bf16 (blocks 0..95) + zero bucket_cnt ------------
__global__ __launch_bounds__(256)
void k_init(const float* __restrict__ Ws, const float* __restrict__ Wd,
            const float* __restrict__ Wl, short* __restrict__ wT,
            int* __restrict__ bucket_cnt, int NBK) {
    const int bid = blockIdx.x, tid = threadIdx.x;
    if (bid < 96) {
        const int idx = bid * 256 + tid;              // 96*256 = 24576 = 192*128
        const int n = idx >> 7, k = idx & 127;
        float v;
        if (n < 64)       v = Ws[k * DOUT + n];
        else if (n < 128) v = Wd[k * DOUT + (n - 64)];
        else              v = Wl[k * DOUT + (n - 128)];
        wT[idx] = (short)f2bf(v);
        return;
    }
    const int i = (bid - 96) * 256 + tid;
    if (i <= NBK) bucket_cnt[i] = 0;
}

// ---------------- fused: node_proj (even blocks) + bucket count (odd) -------
// proj role: 4 waves x 16 nodes = 64 nodes/block. wT staged in LDS ONCE per
// block in MFMA-fragment order (kills the per-wave 48KB L2 re-read that was
// the ~45us invariant). count role: LDS hist over buckets.
__global__ __launch_bounds__(256)
void k_proj_cnt(const float* __restrict__ x, const short* __restrict__ wT,
                const float* __restrict__ bs, const float* __restrict__ bd,
                const float* __restrict__ bl, const float* __restrict__ Wa,
                unsigned short* __restrict__ packed_bf,
                float* __restrict__ xd, float* __restrict__ alpha_s,
                float* __restrict__ alpha_d, float* __restrict__ h_out, int N,
                const int* __restrict__ dst, int* __restrict__ bucket_cnt,
                int E, int NPJ, int NCB, int NBK) {
    __shared__ short xs[64 * 136];                    // 17.4 KB (proj x tile)
    __shared__ short wtl[48 * 512];                   // 48 KB (proj W frags)
    __shared__ int  lhist[392];                       // (count)
    const int bid = blockIdx.x, tid = threadIdx.x;

    if (bid & 1) {
        // ---------------- count role ----------------
        const int ci = bid >> 1;
        if (ci >= NCB) return;
        for (int i = tid; i < NBK; i += 256) lhist[i] = 0;
        __syncthreads();
        const int base0 = ci * 4096;
#pragma unroll
        for (int k = 0; k < 4; ++k) {
            const int e0 = base0 + k * 1024 + tid * 4;
            if (e0 + 3 < E) {
                const int4 d = *(const int4*)&dst[e0];
                atomicAdd(&lhist[d.x >> BKT_SH], 1);
                atomicAdd(&lhist[d.y >> BKT_SH], 1);
                atomicAdd(&lhist[d.z >> BKT_SH], 1);
                atomicAdd(&lhist[d.w >> BKT_SH], 1);
            } else {
                for (int e = e0; e < E; ++e) atomicAdd(&lhist[dst[e] >> BKT_SH], 1);
            }
        }
        __syncthreads();
        for (int i = tid; i < NBK; i += 256)
            if (lhist[i]) atomicAdd(&bucket_cnt[i], lhist[i]);
        return;
    }

    // ---------------- proj role ----------------
    const int pj = bid >> 1;
    if (pj >= NPJ) return;
    const int wave = tid >> 6, lane = tid & 63;
    const int lam = lane & 15, g = lane >> 4;
    const int n0 = pj * 64;

    // stage 64 rows of x as bf16
    {
        const int r = tid >> 2, c0 = (tid & 3) * 32;
        const int nn = n0 + r;
#pragma unroll
        for (int j = 0; j < 8; ++j) {
            float4 v = make_float4(0.f, 0.f, 0.f, 0.f);
            if (nn < N) v = ((const float4*)x)[(size_t)nn * 32 + (c0 >> 2) + j];
            short4 h4;
            h4.x = (short)f2bf(v.x); h4.y = (short)f2bf(v.y);
            h4.z = (short)f2bf(v.z); h4.w = (short)f2bf(v.w);
            *(short4*)&xs[r * 136 + c0 + j * 4] = h4;
        }
    }
    // stage wT into LDS in fragment order: frag f=(c*4+ks), slot = f*64+l,
    // holds global wT[(c*16 + (l&15))*128 + ks*32 + (l>>4)*8 .. +7]
#pragma unroll
    for (int k = 0; k < 12; ++k) {
        const int s = k * 256 + tid;                  // 0..3071
        const int f = s >> 6, l = s & 63;
        const int c = f >> 2, ks = f & 3;
        const int go = (c * 16 + (l & 15)) * 128 + ks * 32 + (l >> 4) * 8;
        *(u16x8*)&wtl[s * 8] = *(const u16x8*)&wT[go];
    }
    __syncthreads();

    bf16x8 afr[4];
#pragma unroll
    for (int ks = 0; ks < 4; ++ks)
        afr[ks] = *(const bf16x8*)&xs[(wave * 16 + lam) * 136 + ks * 32 + g * 8];

    f32x4 acc[12];
#pragma unroll
    for (int c = 0; c < 12; ++c) acc[c] = (f32x4){0.f, 0.f, 0.f, 0.f};

#pragma unroll
    for (int c = 0; c < 12; ++c) {
#pragma unroll
        for (int ks = 0; ks < 4; ++ks) {
            const bf16x8 b = *(const bf16x8*)&wtl[(((c * 4 + ks) << 6) + lane) * 8];
            acc[c] = __builtin_amdgcn_mfma_f32_16x16x32_bf16(afr[ks], b, acc[c], 0, 0, 0);
        }
    }

    float bsv[4], bdv[4], blv[4];
#pragma unroll
    for (int c = 0; c < 4; ++c) {
        bsv[c] = bs[c * 16 + lam];
        bdv[c] = bd[c * 16 + lam];
        blv[c] = bl[c * 16 + lam];
    }
    const float waS = Wa[lam], waD = Wa[16 + lam];
    const int cc_base = (lam >> 2), t_sl = lam & 3;

#pragma unroll
    for (int i = 0; i < 4; ++i) {
        const int node = n0 + wave * 16 + g * 4 + i;
        float xsv[4], xdv[4], hv[4];
#pragma unroll
        for (int c = 0; c < 4; ++c) {
            xsv[c] = acc[c][i]     + bsv[c];
            xdv[c] = acc[4 + c][i] + bdv[c];
            hv[c]  = acc[8 + c][i] + blv[c];
        }
        float p0 = hv[0] * waS, p1 = hv[1] * waS, p2 = hv[2] * waS, p3 = hv[3] * waS;
        float q0 = hv[0] * waD, q1 = hv[1] * waD, q2 = hv[2] * waD, q3 = hv[3] * waD;
#pragma unroll
        for (int off = 1; off < 16; off <<= 1) {
            p0 += __shfl_xor(p0, off); p1 += __shfl_xor(p1, off);
            p2 += __shfl_xor(p2, off); p3 += __shfl_xor(p3, off);
            q0 += __shfl_xor(q0, off); q1 += __shfl_xor(q1, off);
            q2 += __shfl_xor(q2, off); q3 += __shfl_xor(q3, off);
        }
        if (node < N) {
            const size_t rowb = (size_t)node * 128;
#pragma unroll
            for (int c = 0; c < 4; ++c) {
                const int cc = c * 4 + cc_base;
                packed_bf[rowb + cc * 8 + t_sl]     = f2bf(xsv[c]);
                packed_bf[rowb + cc * 8 + 4 + t_sl] = f2bf(hv[c]);
                xd   [(size_t)node * DOUT + c * 16 + lam] = xdv[c];
                h_out[(size_t)node * DOUT + c * 16 + lam] = hv[c];
            }
            if (lam == 0) {
                *(f32x4*)&alpha_s[(size_t)node * NHEAD] = (f32x4){p0, p1, p2, p3};
                *(f32x4*)&alpha_d[(size_t)node * NHEAD] = (f32x4){q0, q1, q2, q3};
            }
        }
    }
}

// ---------------- scan over buckets (single block, <=512 buckets) -----------
__global__ __launch_bounds__(512)
void k_scan_buckets(const int* __restrict__ bucket_cnt,
                    int* __restrict__ bucket_base, int* __restrict__ bucket_cursor,
                    int NBK) {
    __shared__ int wsum[8];
    const int tid = threadIdx.x, lane = tid & 63, wid = tid >> 6;
    int v = (tid < NBK) ? bucket_cnt[tid] : 0;
    int incl = v;
#pragma unroll
    for (int off = 1; off < 64; off <<= 1) {
        int t = __shfl_up(incl, off);
        if (lane >= off) incl += t;
    }
    if (lane == 63) wsum[wid] = incl;
    __syncthreads();
    if (tid < 8) {
        int t = wsum[tid];
#pragma unroll
        for (int off = 1; off < 8; off <<= 1) {
            int u = __shfl_up(t, off);
            if (tid >= off) t += u;
        }
        wsum[tid] = t;
    }
    __syncthreads();
    const int base = (wid > 0) ? wsum[wid - 1] : 0;
    const int excl = incl - v + base;
    if (tid < NBK) {
        bucket_base[tid]   = excl;
        bucket_cursor[tid] = excl;
    }
    if (tid == 0) bucket_base[NBK] = wsum[7];
}

// ---------------- bucket scatter: (src,dst) pairs into bucket regions -------
__global__ __launch_bounds__(256)
void k_bucket_scatter(const int* __restrict__ src, const int* __restrict__ dst,
                      int* __restrict__ bucket_cursor, int2* __restrict__ pairs,
                      int E, int NBK) {
    __shared__ int lhist[392];
    __shared__ int lcur[392];
    const int tid = threadIdx.x;
    const int base0 = blockIdx.x * 4096;
    for (int i = tid; i < NBK; i += 256) lhist[i] = 0;
    __syncthreads();
#pragma unroll
    for (int k = 0; k < 4; ++k) {
        const int e0 = base0 + k * 1024 + tid * 4;
        if (e0 + 3 < E) {
            const int4 d = *(const int4*)&dst[e0];
            atomicAdd(&lhist[d.x >> BKT_SH], 1);
            atomicAdd(&lhist[d.y >> BKT_SH], 1);
            atomicAdd(&lhist[d.z >> BKT_SH], 1);
            atomicAdd(&lhist[d.w >> BKT_SH], 1);
        } else {
            for (int e = e0; e < E; ++e) atomicAdd(&lhist[dst[e] >> BKT_SH], 1);
        }
    }
    __syncthreads();
    for (int i = tid; i < NBK; i += 256)
        lcur[i] = lhist[i] ? atomicAdd(&bucket_cursor[i], lhist[i]) : 0;
    __syncthreads();
#pragma unroll
    for (int k = 0; k < 4; ++k) {
        const int e0 = base0 + k * 1024 + tid * 4;
        if (e0 + 3 < E) {
            const int4 s = *(const int4*)&src[e0];
            const int4 d = *(const int4*)&dst[e0];
            int p;
            p = atomicAdd(&lcur[d.x >> BKT_SH], 1); pairs[p] = make_int2(s.x, d.x);
            p = atomicAdd(&lcur[d.y >> BKT_SH], 1); pairs[p] = make_int2(s.y, d.y);
            p = atomicAdd(&lcur[d.z >> BKT_SH], 1); pairs[p] = make_int2(s.z, d.z);
            p = atomicAdd(&lcur[d.w >> BKT_SH], 1); pairs[p] = make_int2(s.w, d.w);
        } else {
            for (int e = e0; e < E; ++e) {
                const int d = dst[e];
                const int p = atomicAdd(&lcur[d >> BKT_SH], 1);
                pairs[p] = make_int2(src[e], d);
            }
        }
    }
}

// ---------------- per-bucket: degi hist -> row_ptr + ranked srcs write ------
__global__ __launch_bounds__(256)
void k_bucket_rank(const int2* __restrict__ pairs, const int* __restrict__ bucket_base,
                   int* __restrict__ row_ptr, int* __restrict__ srcs,
                   int N, int NBK) {
    __shared__ int hist[BKT_SZ];
    __shared__ int cursor[BKT_SZ];
    __shared__ int wtot[2];
    const int b = blockIdx.x, tid = threadIdx.x;
    const int n0 = b << BKT_SH;
    const int ebase = bucket_base[b];
    const int ecnt  = bucket_base[b + 1] - ebase;

    if (tid < BKT_SZ) hist[tid] = 0;
    __syncthreads();
    for (int i = tid; i < ecnt; i += 256)
        atomicAdd(&hist[pairs[ebase + i].y & (BKT_SZ - 1)], 1);
    __syncthreads();

    int v = 0, incl = 0;
    const int lane = tid & 63, wid = tid >> 6;
    if (tid < BKT_SZ) {
        v = hist[tid];
        incl = v;
#pragma unroll
        for (int off = 1; off < 64; off <<= 1) {
            int t = __shfl_up(incl, off);
            if (lane >= off) incl += t;
        }
        if (lane == 63) wtot[wid] = incl;
    }
    __syncthreads();
    if (tid < BKT_SZ) {
        const int excl = incl - v + ((wid == 1) ? wtot[0] : 0);
        if (n0 + tid < N) row_ptr[n0 + tid] = ebase + excl;
        cursor[tid] = excl;
    }
    if (b == NBK - 1 && tid == 0) row_ptr[N] = bucket_base[NBK];
    __syncthreads();

    for (int i = tid; i < ecnt; i += 256) {
        const int2 pr = pairs[ebase + i];
        const int slot = atomicAdd(&cursor[pr.y & (BKT_SZ - 1)], 1);
        srcs[ebase + slot] = pr.x;
    }
}

// ---------------- fused per-dst aggregation: 1 node/wave, 4 edges/iter ------
// lane = (g=edge group, hd=lam>>2, q=lam&3); lane owns dims hd*16+q*4..+3.
// prefetch distance 3 (rotating pipeline: 32 VGPR, no spill).
__global__ __launch_bounds__(256, 8)
void k_aggregate(const int* __restrict__ row_ptr, const int* __restrict__ srcs,
                 const unsigned short* __restrict__ packed_bf, // [N][128]
                 const float* __restrict__ xd,                 // [N][64]
                 const float* __restrict__ alpha_s, const float* __restrict__ alpha_d,
                 const float* __restrict__ Wa, const float* __restrict__ ba,
                 float* __restrict__ edge_s, float* __restrict__ out, int N) {
    const int lane = threadIdx.x & 63;
    const int n = blockIdx.x * 4 + (threadIdx.x >> 6);
    if (n >= N) return;
    const int g = lane >> 4, lam = lane & 15;
    const int hd = lam >> 2, q = lam & 3;

    const int start = row_ptr[n];
    const int end   = row_ptr[n + 1];
    const int deg = end - start;
    const int last = end - 1;

    const float4 xd4 = *(const float4*)&xd[(size_t)n * DOUT + lam * 4];
    const float4 wa4 = *(const float4*)&Wa[32 + q * 4];
    const float adb  = alpha_d[n * NHEAD + hd] + ba[0];

    float es0=0.f,es1=0.f,es2=0.f,es3=0.f;
    float o0=0.f,o1=0.f,o2=0.f,o3=0.f;
    float s = 0.f;

    const int niter = (deg + 3) >> 2;
    int e = start + g;

    float vm0=0.f, vm1=0.f, vm2=0.f;
    u16x8 pk0=(u16x8){0,0,0,0,0,0,0,0}, pk1=pk0, pk2=pk0;
    float as0=0.f, as1=0.f, as2=0.f;
    if (niter > 0) {
        {
            vm0 = (e < end) ? 1.f : 0.f;
            const int sn = srcs[min(e, last)];
            pk0 = *(const u16x8*)&packed_bf[(size_t)sn * 128 + lam * 8];
            as0 = alpha_s[sn * NHEAD + hd];
        }
        {
            const int e1 = e + 4;
            vm1 = (e1 < end) ? 1.f : 0.f;
            const int sn = srcs[min(e1, last)];
            pk1 = *(const u16x8*)&packed_bf[(size_t)sn * 128 + lam * 8];
            as1 = alpha_s[sn * NHEAD + hd];
        }
        {
            const int e2 = e + 8;
            vm2 = (e2 < end) ? 1.f : 0.f;
            const int sn = srcs[min(e2, last)];
            pk2 = *(const u16x8*)&packed_bf[(size_t)sn * 128 + lam * 8];
            as2 = alpha_s[sn * NHEAD + hd];
        }
    }

    for (int it = 0; it < niter; ++it) {
        float vmn = 0.f, asn = 0.f;
        u16x8 pkn = (u16x8){0,0,0,0,0,0,0,0};
        const int e3 = e + 12;
        if (it + 3 < niter) {
            vmn = (e3 < end) ? 1.f : 0.f;
            const int sn = srcs[min(e3, last)];
            pkn = *(const u16x8*)&packed_bf[(size_t)sn * 128 + lam * 8];
            asn = alpha_s[sn * NHEAD + hd];
        }

        const float t0 = __expf(2.f * (bf2f(pk0[0]) + xd4.x));
        const float t1 = __expf(2.f * (bf2f(pk0[1]) + xd4.y));
        const float t2 = __expf(2.f * (bf2f(pk0[2]) + xd4.z));
        const float t3 = __expf(2.f * (bf2f(pk0[3]) + xd4.w));
        const float er0 = fmaf(-2.f, __builtin_amdgcn_rcpf(t0 + 1.f), 1.f);
        const float er1 = fmaf(-2.f, __builtin_amdgcn_rcpf(t1 + 1.f), 1.f);
        const float er2 = fmaf(-2.f, __builtin_amdgcn_rcpf(t2 + 1.f), 1.f);
        const float er3 = fmaf(-2.f, __builtin_amdgcn_rcpf(t3 + 1.f), 1.f);
        es0 = fmaf(er0, vm0, es0); es1 = fmaf(er1, vm0, es1);
        es2 = fmaf(er2, vm0, es2); es3 = fmaf(er3, vm0, es3);

        float p = er0 * wa4.x;
        p = fmaf(er1, wa4.y, p);
        p = fmaf(er2, wa4.z, p);
        p = fmaf(er3, wa4.w, p);
        p += __shfl_xor(p, 1);
        p += __shfl_xor(p, 2);

        float a = as0 + adb + p;
        a = (a >= 0.f) ? a : 0.01f * a;            // leaky relu
        const float w = __expf(a) * vm0;
        s += w;
        o0 = fmaf(w, bf2f(pk0[4]), o0); o1 = fmaf(w, bf2f(pk0[5]), o1);
        o2 = fmaf(w, bf2f(pk0[6]), o2); o3 = fmaf(w, bf2f(pk0[7]), o3);

        vm0 = vm1; pk0 = pk1; as0 = as1;
        vm1 = vm2; pk1 = pk2; as1 = as2;
        vm2 = vmn; pk2 = pkn; as2 = asn;
        e += 4;
    }

#pragma unroll
    for (int off = 16; off < 64; off <<= 1) {
        es0 += __shfl_xor(es0, off); es1 += __shfl_xor(es1, off);
        es2 += __shfl_xor(es2, off); es3 += __shfl_xor(es3, off);
        o0  += __shfl_xor(o0,  off); o1  += __shfl_xor(o1,  off);
        o2  += __shfl_xor(o2,  off); o3  += __shfl_xor(o3,  off);
        s   += __shfl_xor(s,   off);
    }

    if (g == 0) {
        const float inv_s = __builtin_amdgcn_rcpf(fmaxf(s, 1e-38f));
        const float inv_d = __builtin_amdgcn_rcpf(fmaxf((float)deg, 1.0f));
        const size_t od = (size_t)n * DOUT + lam * 4;
        *(f32x4*)&out[od]    = (f32x4){o0 * inv_s, o1 * inv_s, o2 * inv_s, o3 * inv_s};
        *(f32x4*)&edge_s[od] = (f32x4){es0 * inv_d, es1 * inv_d, es2 * inv_d, es3 * inv_d};
    }
}

extern "C" void kernel_launch(void* const* d_in, const int* in_sizes, int n_in,
                              void* d_out, int out_size, void* d_ws, size_t ws_size,
                              hipStream_t stream) {
    const float* x  = (const float*)d_in[0];
    const int*   src= (const int*)  d_in[1];
    const int*   dst= (const int*)  d_in[2];
    const float* Ws = (const float*)d_in[3];
    const float* bs = (const float*)d_in[4];
    const float* Wd = (const float*)d_in[5];
    const float* bd = (const float*)d_in[6];
    const float* Wl = (const float*)d_in[7];
    const float* bl = (const float*)d_in[8];
    const float* Wa = (const float*)d_in[9];
    const float* ba = (const float*)d_in[10];

    const int N = in_sizes[0] / DIN;
    const int E = in_sizes[1];
    const int NBK = (N + BKT_SZ - 1) >> BKT_SH;       // buckets (<=512)

    float* out_f = (float*)d_out;
    float* edge_s_out = out_f;                        // chunk 0: [N,64]
    float* out_attn   = out_f + (size_t)N * DOUT;     // chunk 1: [N,64]
    float* h_out      = out_f + 2 * (size_t)N * DOUT; // chunk 2: [N,64]

    char* ws = (char*)d_ws;
    size_t o = 0;
    unsigned short* packed_bf = (unsigned short*)(ws + o); o += (size_t)N * 128 * 2;
    float* xd      = (float*)(ws + o); o += (size_t)N * DOUT * 4;
    float* alpha_s = (float*)(ws + o); o += (size_t)N * NHEAD * 4;
    float* alpha_d = (float*)(ws + o); o += (size_t)N * NHEAD * 4;
    int*   row_ptr = (int*)  (ws + o); o += (size_t)(N + 1) * 4;
    int*   srcs    = (int*)  (ws + o); o += (size_t)E * 4;
    int2*  pairs   = (int2*) (ws + o); o += (size_t)E * 8;
    int*   bucket_cnt    = (int*)(ws + o); o += 512 * 4;
    int*   bucket_base   = (int*)(ws + o); o += 513 * 4;
    int*   bucket_cursor = (int*)(ws + o); o += 512 * 4;
    short* wT      = (short*)(ws + o); o += (size_t)192 * 128 * 2;

    k_init<<<96 + (NBK + 256) / 256, 256, 0, stream>>>(Ws, Wd, Wl, wT, bucket_cnt, NBK);

    const int NPJ = (N + 63) / 64;             // proj blocks (64 nodes each)
    const int NCB = (E + 4095) / 4096;         // count blocks (4096 edges each)
    const int GC  = 2 * ((NPJ > NCB) ? NPJ : NCB);
    k_proj_cnt<<<GC, 256, 0, stream>>>(x, wT, bs, bd, bl, Wa,
                                       packed_bf, xd, alpha_s, alpha_d, h_out, N,
                                       dst, bucket_cnt, E, NPJ, NCB, NBK);

    k_scan_buckets<<<1, 512, 0, stream>>>(bucket_cnt, bucket_base, bucket_cursor, NBK);

    k_bucket_scatter<<<NCB, 256, 0, stream>>>(src, dst, bucket_cursor, pairs, E, NBK);

    k_bucket_rank<<<NBK, 256, 0, stream>>>(pairs, bucket_base, row_ptr, srcs, N, NBK);

    k_aggregate<<<(N + 3) / 4, 256, 0, stream>>>(row_ptr, srcs, packed_bf, xd,
                                                 alpha_s, alpha_d, Wa, ba,
                                                 edge_s_out, out_attn, N);
}